// Round 8
// baseline (167.476 us; speedup 1.0000x reference)
//
#include <hip/hip_runtime.h>
#include <hip/hip_bf16.h>

// ParallelNCA on MFMA: 64 grouped MLPs (144->128->16) over 3x3 perception.
// Round 8: round 7 + non-temporal loads/stores on all stream-once traffic
// (prep x read, xbf/weight writes, main residual-x read, out write) so L2
// keeps the REUSED data (xbf gather reads, bf16 weights) resident.

typedef __attribute__((ext_vector_type(8))) short short8;   // 8 bf16 frag
typedef __attribute__((ext_vector_type(4))) float f32x4;    // MFMA acc
typedef __attribute__((ext_vector_type(2))) uint  u32x2;

constexpr int Bn  = 16;
constexpr int Mn  = 64;
constexpr int Cn  = 16;
constexpr int Hd  = 128;
constexpr int K9  = 144;
constexpr int MCn = 1024;
constexpr int NP  = 128;        // pixels per block (4 image rows)
constexpr int PT_STRIDE = 304;  // bytes/pixel row of Pt (76 words; 16B-mult)
constexpr int HT_STRIDE = 272;  // bytes/pixel row of Ht
constexpr int NT  = 256;

// padded bf16 x: [b][mc][34 rows][40 ushorts] ; row h stored at h+1, col w at w+4
constexpr int XROW = 80;            // bytes per padded row
constexpr int XCH  = 34 * XROW;     // 2720 B per channel
constexpr size_t XBF_BYTES = (size_t)Bn * MCn * XCH;            // 44,564,480
constexpr size_t W1_ELEMS  = (size_t)Mn * Hd * K9;              // 1,179,648
constexpr size_t W2_ELEMS  = (size_t)Mn * Cn * Hd;              // 131,072
constexpr size_t WS_NEED   = XBF_BYTES + 2 * (W1_ELEMS + W2_ELEMS);

__device__ __forceinline__ ushort f2bf(float f) {
    return __bfloat16_as_ushort(__float2bfloat16(f));
}

// ---------------------------------------------------------------------------
// prep: x (f32 [b][mc][32][32]) -> xbf (bf16 padded [b*mc][34][40], zero borders)
// ---------------------------------------------------------------------------
__global__ __launch_bounds__(256)
void prep_x(const float* __restrict__ x, ushort* __restrict__ xbf)
{
    const int blk = blockIdx.x;          // b*1024 + mc
    const int tid = threadIdx.x;
    char* chbase = (char*)xbf + (size_t)blk * XCH;

    // borders (disjoint from interior writes -> no barrier needed)
    if (tid < 168) {
        if (tid < 40) {
            const int r = (tid < 20) ? 0 : 33;
            const int jq = tid % 20;
            __builtin_nontemporal_store(0u, (uint*)(chbase + r * XROW + 4 * jq));
        } else {
            const int e = tid - 40;
            const int r = 1 + (e >> 2);
            const int jq = (e & 2) ? (18 + (e & 1)) : (e & 1);
            __builtin_nontemporal_store(0u, (uint*)(chbase + r * XROW + 4 * jq));
        }
    }
    // interior: thread -> (h = tid>>3, 4-px quad q = tid&7)
    const int h = tid >> 3, q = tid & 7;
    const f32x4 f = __builtin_nontemporal_load(
        (const f32x4*)(x + ((size_t)blk * 32 + h) * 32 + 4 * q));
    u32x2 pk;
    pk.x = (uint)f2bf(f[0]) | ((uint)f2bf(f[1]) << 16);
    pk.y = (uint)f2bf(f[2]) | ((uint)f2bf(f[3]) << 16);
    __builtin_nontemporal_store(pk, (u32x2*)(chbase + (h + 1) * XROW + 8 * q + 8));
}

// ---------------------------------------------------------------------------
// prep: weights f32 -> bf16 (same layouts)
// ---------------------------------------------------------------------------
__global__ __launch_bounds__(256)
void prep_w(const float* __restrict__ w1, const float* __restrict__ w2,
            ushort* __restrict__ w1bf, ushort* __restrict__ w2bf)
{
    const size_t i = ((size_t)blockIdx.x * 256 + threadIdx.x) * 4;
    const float* src; ushort* dst; size_t e;
    if (i < W1_ELEMS) { src = w1; dst = w1bf; e = i; }
    else              { src = w2; dst = w2bf; e = i - W1_ELEMS; }
    const f32x4 f = __builtin_nontemporal_load((const f32x4*)(src + e));
    u32x2 pk;
    pk.x = (uint)f2bf(f[0]) | ((uint)f2bf(f[1]) << 16);
    pk.y = (uint)f2bf(f[2]) | ((uint)f2bf(f[3]) << 16);
    __builtin_nontemporal_store(pk, (u32x2*)(dst + e));
}

// ---------------------------------------------------------------------------
// main kernel (bf16 source)
// ---------------------------------------------------------------------------
__global__ __launch_bounds__(NT, 4)
void nca_mfma_bf16(const float* __restrict__ x, const ushort* __restrict__ xbf,
                   const ushort* __restrict__ w1bf, const float* __restrict__ b1,
                   const ushort* __restrict__ w2bf, const float* __restrict__ b2,
                   float* __restrict__ out)
{
    // union: Pt[p][kp] bf16 perception; then Ht[p][hd] bf16 hidden; then dxT f32.
    __shared__ __align__(16) char U[NP * PT_STRIDE + 16];
    char* const PtL = U;
    char* const HtL = U;

    const int tid  = threadIdx.x;
    const int lane = tid & 63;
    const int wid  = tid >> 6;      // wave 0..3
    const int lr   = lane & 15;     // MFMA row/col lane index
    const int lk   = lane >> 4;     // MFMA k-group 0..3

    // XCD-group swizzle (round 4: kept, faster)
    const int bid = blockIdx.x;
    const int xcd = bid & 7;
    const int jb  = bid >> 3;
    const int m   = jb & 63;                // model 0..63
    const int g   = (jb >> 6) * 8 + xcd;    // pixel group 0..127
    const int b   = g >> 3;                 // batch 0..15
    const int p0  = (g & 7) * NP;           // pixel base within image

    // zero k-pad columns (NaN guard for MFMA's 0*garbage) + guard row
    if (tid <= NP) {
        char* z = PtL + tid * PT_STRIDE + (tid < NP ? 288 : 0);
        *(int4*)z = (int4){0, 0, 0, 0};
    }

    // ---------- w1 bf16 A-frags ----------
    short8 a1[2][5];
    #pragma unroll
    for (int rt = 0; rt < 2; ++rt) {
        const int row = wid * 32 + rt * 16 + lr;
        const ushort* wr = w1bf + (m * Hd + row) * K9;
        #pragma unroll
        for (int ks = 0; ks < 5; ++ks) {
            const int k0 = ks * 32 + lk * 8;
            a1[rt][ks] = (k0 < K9) ? *(const short8*)(wr + k0)
                                   : (short8){0,0,0,0,0,0,0,0};
        }
    }
    // ---------- w2 bf16 A-frags ----------
    short8 a2[4];
    #pragma unroll
    for (int ks = 0; ks < 4; ++ks)
        a2[ks] = *(const short8*)(w2bf + (m * Cn + lr) * Hd + ks * 32 + lk * 8);

    // ---------- gather: xbf -> Pt[p][kp] (packed bf16 channel-pairs) ----------
    // thread = (s2 = 8-px strip 0..3, kpl 0..15, r = row 0..3). 5 iters
    // (last half-active). Loads: 2x uint4 per channel, 16B-aligned.
    {
        const int s2  = tid & 3;
        const int kpl = (tid >> 2) & 15;
        const int r   = tid >> 6;
        const int rbase = (g & 7) * 4 + r;
        const char* xbc = (const char*)xbf + (size_t)b * (MCn * XCH);
        const unsigned long long TAB = 0xA62918405ull;  // (dr+1)|((dc+1)<<2) per shift
        char* const dstrow = PtL + (r * 32 + 8 * s2) * PT_STRIDE;
        const int s2B = s2 * PT_STRIDE;

        #pragma unroll
        for (int it = 0; it < 5; ++it) {
            const int kp = it * 16 + kpl;        // 0..79; active < 72
            if (kp < 72) {
                uint rr[2][4];
                #pragma unroll
                for (int half = 0; half < 2; ++half) {
                    const int ch = m * K9 + kp * 2 + half;
                    const int sh = ch >> 10;
                    const int mc = ch & 1023;
                    const uint nib = (uint)(TAB >> (4 * sh)) & 15u;
                    const int dr = (int)(nib & 3u) - 1;
                    const int dc = (int)(nib >> 2) - 1;
                    const char* rp = xbc + (mc * 34 + rbase + dr + 1) * XROW + 16 * s2;
                    const uint4 va = *(const uint4*)(rp);
                    const uint4 vb = *(const uint4*)(rp + 16);
                    // extract ushorts [o, o+8), o = 4+dc in {3,4,5}
                    const int o  = 4 + dc;
                    const uint shb = (uint)((o & 1) << 4);
                    const bool hiq = (o >> 1) == 2;
                    const uint e0 = hiq ? va.z : va.y;
                    const uint e1 = hiq ? va.w : va.z;
                    const uint e2 = hiq ? vb.x : va.w;
                    const uint e3 = hiq ? vb.y : vb.x;
                    const uint e4 = hiq ? vb.z : vb.y;
                    rr[half][0] = __builtin_amdgcn_alignbit(e1, e0, shb);
                    rr[half][1] = __builtin_amdgcn_alignbit(e2, e1, shb);
                    rr[half][2] = __builtin_amdgcn_alignbit(e3, e2, shb);
                    rr[half][3] = __builtin_amdgcn_alignbit(e4, e3, shb);
                }
                // interleave: out_px pairs (ch0|ch1<<16)
                uint o0 = __builtin_amdgcn_perm(rr[1][0], rr[0][0], 0x05040100u);
                uint o1 = __builtin_amdgcn_perm(rr[1][0], rr[0][0], 0x07060302u);
                uint o2 = __builtin_amdgcn_perm(rr[1][1], rr[0][1], 0x05040100u);
                uint o3 = __builtin_amdgcn_perm(rr[1][1], rr[0][1], 0x07060302u);
                uint o4 = __builtin_amdgcn_perm(rr[1][2], rr[0][2], 0x05040100u);
                uint o5 = __builtin_amdgcn_perm(rr[1][2], rr[0][2], 0x07060302u);
                uint o6 = __builtin_amdgcn_perm(rr[1][3], rr[0][3], 0x05040100u);
                uint o7 = __builtin_amdgcn_perm(rr[1][3], rr[0][3], 0x07060302u);
                // rotate tuple left by s2 (banks: 76*drow mod 32 spreads lanes)
                const bool c1 = s2 & 1, c2 = s2 & 2;
                uint n0 = c1 ? o1 : o0, n1 = c1 ? o2 : o1, n2 = c1 ? o3 : o2,
                     n3 = c1 ? o4 : o3, n4 = c1 ? o5 : o4, n5 = c1 ? o6 : o5,
                     n6 = c1 ? o7 : o6, n7 = c1 ? o0 : o7;
                uint t0 = c2 ? n2 : n0, t1 = c2 ? n3 : n1, t2 = c2 ? n4 : n2,
                     t3 = c2 ? n5 : n3, t4 = c2 ? n6 : n4, t5 = c2 ? n7 : n5,
                     t6 = c2 ? n0 : n6, t7 = c2 ? n1 : n7;
                char* const dstb = dstrow + kp * 4;
                #pragma unroll
                for (int j2 = 0; j2 < 8; ++j2) {
                    int off = s2B + j2 * PT_STRIDE;
                    if (off >= 8 * PT_STRIDE) off -= 8 * PT_STRIDE;
                    const uint val = (j2 == 0) ? t0 : (j2 == 1) ? t1 : (j2 == 2) ? t2 :
                                     (j2 == 3) ? t3 : (j2 == 4) ? t4 : (j2 == 5) ? t5 :
                                     (j2 == 6) ? t6 : t7;
                    *(uint*)(dstb + off) = val;
                }
            }
        }
    }
    __syncthreads();

    // ---------- GEMM1: hdn = w1 @ P, 128x128x160 ----------
    f32x4 acc[2][8];
    #pragma unroll
    for (int i = 0; i < 2; ++i)
        #pragma unroll
        for (int jj = 0; jj < 8; ++jj) acc[i][jj] = (f32x4){0.f, 0.f, 0.f, 0.f};

    #pragma unroll
    for (int ct = 0; ct < 8; ++ct) {
        const int p = ct * 16 + lr;
        const char* base = PtL + p * PT_STRIDE + lk * 16;
        short8 bfrag[5];
        #pragma unroll
        for (int ks = 0; ks < 5; ++ks)
            bfrag[ks] = *(const short8*)(base + ks * 64);
        #pragma unroll
        for (int ks = 0; ks < 5; ++ks) {
            acc[0][ct] = __builtin_amdgcn_mfma_f32_16x16x32_bf16(a1[0][ks], bfrag[ks], acc[0][ct], 0, 0, 0);
            acc[1][ct] = __builtin_amdgcn_mfma_f32_16x16x32_bf16(a1[1][ks], bfrag[ks], acc[1][ct], 0, 0, 0);
        }
    }
    __syncthreads();   // Pt reads done -> reuse U as Ht

    // ---------- bias+relu -> Ht[p][hd] bf16 ----------
    #pragma unroll
    for (int rt = 0; rt < 2; ++rt) {
        const int hd0 = wid * 32 + rt * 16 + lk * 4;   // C/D row = (lane>>4)*4 + reg
        const float4 bs = *(const float4*)(b1 + m * Hd + hd0);
        #pragma unroll
        for (int ct = 0; ct < 8; ++ct) {
            const int p = ct * 16 + lr;                // C/D col = lane&15
            const f32x4 v = acc[rt][ct];
            uint2 pk;
            pk.x = (uint)f2bf(fmaxf(v[0] + bs.x, 0.f)) |
                   ((uint)f2bf(fmaxf(v[1] + bs.y, 0.f)) << 16);
            pk.y = (uint)f2bf(fmaxf(v[2] + bs.z, 0.f)) |
                   ((uint)f2bf(fmaxf(v[3] + bs.w, 0.f)) << 16);
            *(uint2*)(HtL + p * HT_STRIDE + hd0 * 2) = pk;
        }
    }
    __syncthreads();

    // ---------- GEMM2: dx = w2 @ hdn, 16x128x128 ----------
    f32x4 acc2[2];
    #pragma unroll
    for (int jj = 0; jj < 2; ++jj) {
        const int ct = wid * 2 + jj;
        const int p  = ct * 16 + lr;
        const char* base = HtL + p * HT_STRIDE + lk * 16;
        short8 bb[4];
        #pragma unroll
        for (int ks = 0; ks < 4; ++ks)
            bb[ks] = *(const short8*)(base + ks * 64);
        f32x4 a = (f32x4){0.f, 0.f, 0.f, 0.f};
        #pragma unroll
        for (int ks = 0; ks < 4; ++ks)
            a = __builtin_amdgcn_mfma_f32_16x16x32_bf16(a2[ks], bb[ks], a, 0, 0, 0);
        acc2[jj] = a;
    }
    __syncthreads();   // Ht reads done -> reuse U as dxT

    // ---------- epilogue: dxT stage -> contiguous 512B out writes (nt) ----------
    const float4 b2v = *(const float4*)(b2 + m * Cn + lk * 4);
    float (*dxT)[132] = (float(*)[132])U;   // 16 x 132 f32 (8448 B)
    {
        const float bsv[4] = {b2v.x, b2v.y, b2v.z, b2v.w};
        #pragma unroll
        for (int jj = 0; jj < 2; ++jj) {
            const int px = (wid * 2 + jj) * 16 + lr;
            #pragma unroll
            for (int rr2 = 0; rr2 < 4; ++rr2)
                dxT[lk * 4 + rr2][px] = acc2[jj][rr2] + bsv[rr2];
        }
    }
    __syncthreads();
    {
        const int c = tid >> 4, iq = tid & 15;
        const int px0 = 8 * iq;
        const f32x4 d0 = *(const f32x4*)&dxT[c][px0];
        const f32x4 d1 = *(const f32x4*)&dxT[c][px0 + 4];
        const size_t idx = ((size_t)(b * MCn + m * Cn + c)) * 1024 + p0 + px0;
        const f32x4 x0 = __builtin_nontemporal_load((const f32x4*)(x + idx));
        const f32x4 x1 = __builtin_nontemporal_load((const f32x4*)(x + idx + 4));
        __builtin_nontemporal_store(x0 + d0, (f32x4*)(out + idx));
        __builtin_nontemporal_store(x1 + d1, (f32x4*)(out + idx + 4));
    }
}

// ---------------------------------------------------------------------------
// fallback (round 6 verbatim): used when ws_size < WS_NEED
// ---------------------------------------------------------------------------
__global__ __launch_bounds__(NT, 4)
void nca_mfma_f32src(const float* __restrict__ x,  const float* __restrict__ w1,
                     const float* __restrict__ b1, const float* __restrict__ w2,
                     const float* __restrict__ b2, float* __restrict__ out)
{
    __shared__ __align__(16) char U[NP * PT_STRIDE + 16];
    char* const PtL = U;
    char* const HtL = U;

    const int tid  = threadIdx.x;
    const int lane = tid & 63;
    const int wid  = tid >> 6;
    const int lr   = lane & 15;
    const int lk   = lane >> 4;

    const int bid = blockIdx.x;
    const int xcd = bid & 7;
    const int jb  = bid >> 3;
    const int m   = jb & 63;
    const int g   = (jb >> 6) * 8 + xcd;
    const int b   = g >> 3;
    const int p0  = (g & 7) * NP;

    if (tid <= NP) {
        char* z = PtL + tid * PT_STRIDE + (tid < NP ? 288 : 0);
        *(int4*)z = (int4){0, 0, 0, 0};
    }

    short8 a1[2][5];
    #pragma unroll
    for (int rt = 0; rt < 2; ++rt) {
        const int row = wid * 32 + rt * 16 + lr;
        const float* wr = w1 + (m * Hd + row) * K9;
        #pragma unroll
        for (int ks = 0; ks < 5; ++ks) {
            const int k0 = ks * 32 + lk * 8;
            short8 t;
            if (k0 < K9) {
                const float4 f0 = *(const float4*)(wr + k0);
                const float4 f1 = *(const float4*)(wr + k0 + 4);
                t[0] = (short)f2bf(f0.x); t[1] = (short)f2bf(f0.y);
                t[2] = (short)f2bf(f0.z); t[3] = (short)f2bf(f0.w);
                t[4] = (short)f2bf(f1.x); t[5] = (short)f2bf(f1.y);
                t[6] = (short)f2bf(f1.z); t[7] = (short)f2bf(f1.w);
            } else t = (short8){0,0,0,0,0,0,0,0};
            a1[rt][ks] = t;
        }
    }
    short8 a2[4];
    #pragma unroll
    for (int ks = 0; ks < 4; ++ks) {
        const float* wr = w2 + (m * Cn + lr) * Hd + ks * 32 + lk * 8;
        const float4 f0 = *(const float4*)(wr);
        const float4 f1 = *(const float4*)(wr + 4);
        short8 t;
        t[0] = (short)f2bf(f0.x); t[1] = (short)f2bf(f0.y);
        t[2] = (short)f2bf(f0.z); t[3] = (short)f2bf(f0.w);
        t[4] = (short)f2bf(f1.x); t[5] = (short)f2bf(f1.y);
        t[6] = (short)f2bf(f1.z); t[7] = (short)f2bf(f1.w);
        a2[ks] = t;
    }
    {
        const int s     = tid & 7;
        const int kpl   = (tid >> 3) & 7;
        const int r     = tid >> 6;
        const int rbase = (g & 7) * 4 + r;
        const float* xb = x + (size_t)b * (MCn * 1024);
        const unsigned long long TAB = 0xA62918405ull;
        #pragma unroll
        for (int it = 0; it < 9; ++it) {
            const int kp = it * 8 + kpl;
            float4 hv[2];
            #pragma unroll
            for (int half = 0; half < 2; ++half) {
                const int ch = m * K9 + kp * 2 + half;
                const int sh = ch >> 10;
                const int mc = ch & 1023;
                const uint nib = (uint)(TAB >> (4 * sh)) & 15u;
                const int dr = (int)(nib & 3u) - 1;
                const int dc = (int)(nib >> 2) - 1;
                const int row = rbase + dr;
                const int wb  = 4 * s + dc;
                const int wc  = min(max(wb, 0), 28);
                float4 f = {0.f, 0.f, 0.f, 0.f};
                if ((unsigned)row < 32u)
                    f = *(const float4*)(xb + (mc * 32 + row) * 32 + wc);
                if (wb < 0)       { f.w = f.z; f.z = f.y; f.y = f.x; f.x = 0.f; }
                else if (wb > 28) { f.x = f.y; f.y = f.z; f.z = f.w; f.w = 0.f; }
                hv[half] = f;
            }
            char* dst = PtL + (r * 32 + 4 * s) * PT_STRIDE + kp * 4;
            *(uint*)(dst)                 = (uint)f2bf(hv[0].x) | ((uint)f2bf(hv[1].x) << 16);
            *(uint*)(dst + PT_STRIDE)     = (uint)f2bf(hv[0].y) | ((uint)f2bf(hv[1].y) << 16);
            *(uint*)(dst + 2 * PT_STRIDE) = (uint)f2bf(hv[0].z) | ((uint)f2bf(hv[1].z) << 16);
            *(uint*)(dst + 3 * PT_STRIDE) = (uint)f2bf(hv[0].w) | ((uint)f2bf(hv[1].w) << 16);
        }
    }
    __syncthreads();

    f32x4 acc[2][8];
    #pragma unroll
    for (int i = 0; i < 2; ++i)
        #pragma unroll
        for (int jj = 0; jj < 8; ++jj) acc[i][jj] = (f32x4){0.f, 0.f, 0.f, 0.f};
    #pragma unroll
    for (int ct = 0; ct < 8; ++ct) {
        const int p = ct * 16 + lr;
        const char* base = PtL + p * PT_STRIDE + lk * 16;
        short8 bfrag[5];
        #pragma unroll
        for (int ks = 0; ks < 5; ++ks)
            bfrag[ks] = *(const short8*)(base + ks * 64);
        #pragma unroll
        for (int ks = 0; ks < 5; ++ks) {
            acc[0][ct] = __builtin_amdgcn_mfma_f32_16x16x32_bf16(a1[0][ks], bfrag[ks], acc[0][ct], 0, 0, 0);
            acc[1][ct] = __builtin_amdgcn_mfma_f32_16x16x32_bf16(a1[1][ks], bfrag[ks], acc[1][ct], 0, 0, 0);
        }
    }
    __syncthreads();
    #pragma unroll
    for (int rt = 0; rt < 2; ++rt) {
        const int hd0 = wid * 32 + rt * 16 + lk * 4;
        const float4 bs = *(const float4*)(b1 + m * Hd + hd0);
        #pragma unroll
        for (int ct = 0; ct < 8; ++ct) {
            const int p = ct * 16 + lr;
            const f32x4 v = acc[rt][ct];
            uint2 pk;
            pk.x = (uint)f2bf(fmaxf(v[0] + bs.x, 0.f)) |
                   ((uint)f2bf(fmaxf(v[1] + bs.y, 0.f)) << 16);
            pk.y = (uint)f2bf(fmaxf(v[2] + bs.z, 0.f)) |
                   ((uint)f2bf(fmaxf(v[3] + bs.w, 0.f)) << 16);
            *(uint2*)(HtL + p * HT_STRIDE + hd0 * 2) = pk;
        }
    }
    __syncthreads();
    f32x4 acc2[2];
    #pragma unroll
    for (int jj = 0; jj < 2; ++jj) {
        const int ct = wid * 2 + jj;
        const int p  = ct * 16 + lr;
        const char* base = HtL + p * HT_STRIDE + lk * 16;
        short8 bb[4];
        #pragma unroll
        for (int ks = 0; ks < 4; ++ks)
            bb[ks] = *(const short8*)(base + ks * 64);
        f32x4 a = (f32x4){0.f, 0.f, 0.f, 0.f};
        #pragma unroll
        for (int ks = 0; ks < 4; ++ks)
            a = __builtin_amdgcn_mfma_f32_16x16x32_bf16(a2[ks], bb[ks], a, 0, 0, 0);
        acc2[jj] = a;
    }
    const float4 b2v = *(const float4*)(b2 + m * Cn + lk * 4);
    const float bsv[4] = {b2v.x, b2v.y, b2v.z, b2v.w};
    #pragma unroll
    for (int jj = 0; jj < 2; ++jj) {
        const int ct = wid * 2 + jj;
        const int gp = p0 + ct * 16 + lr;
        #pragma unroll
        for (int r = 0; r < 4; ++r) {
            const int c   = lk * 4 + r;
            const size_t idx = ((size_t)(b * MCn + m * Cn + c)) * 1024 + gp;
            out[idx] = x[idx] + acc2[jj][r] + bsv[r];
        }
    }
}

extern "C" void kernel_launch(void* const* d_in, const int* in_sizes, int n_in,
                              void* d_out, int out_size, void* d_ws, size_t ws_size,
                              hipStream_t stream)
{
    const float* x  = (const float*)d_in[0];
    const float* w1 = (const float*)d_in[1];
    const float* b1 = (const float*)d_in[2];
    const float* w2 = (const float*)d_in[3];
    const float* b2 = (const float*)d_in[4];
    float* out = (float*)d_out;
    const int grid = Mn * (Bn * 1024 / NP);   // 8192

    if (ws_size >= WS_NEED) {
        ushort* xbf  = (ushort*)d_ws;
        ushort* w1bf = (ushort*)((char*)d_ws + XBF_BYTES);
        ushort* w2bf = w1bf + W1_ELEMS;
        prep_x<<<Bn * MCn, 256, 0, stream>>>(x, xbf);
        prep_w<<<(int)((W1_ELEMS + W2_ELEMS) / 4 / 256), 256, 0, stream>>>(w1, w2, w1bf, w2bf);
        nca_mfma_bf16<<<grid, NT, 0, stream>>>(x, xbf, w1bf, b1, w2bf, b2, out);
    } else {
        nca_mfma_f32src<<<grid, NT, 0, stream>>>(x, w1, b1, w2, b2, out);
    }
}

// Round 10
// 151.035 us; speedup vs baseline: 1.1089x; 1.1089x over previous
//
#include <hip/hip_runtime.h>
#include <hip/hip_bf16.h>

// ParallelNCA on MFMA: 64 grouped MLPs (144->128->16) over 3x3 perception.
// Round 10 = round 9 with prep_xpm write-phase bug fixed (covered only 64/256
// channels -> 3/4 of xpm was poison; now 4 reps cover all 256 mc x 32 w).
//  - pixel-major padded bf16 x (xpm[b][34][34][1024]) in d_ws.
//  - Pt row = TWO contiguous runs of xpm (m-window crosses <=1 shift boundary,
//    boundaries 32B-aligned): gather = 9 uint4 copies/thread, no repack.
//  - residual read from xpm (bf16, L2-hot) -> main kernel never reads f32 x.

typedef __attribute__((ext_vector_type(8))) short short8;   // 8 bf16 frag
typedef __attribute__((ext_vector_type(4))) float f32x4;    // MFMA acc

constexpr int Bn  = 16;
constexpr int Mn  = 64;
constexpr int Cn  = 16;
constexpr int Hd  = 128;
constexpr int K9  = 144;
constexpr int MCn = 1024;
constexpr int NP  = 128;        // pixels per block (4 image rows)
constexpr int PT_STRIDE = 304;  // bytes/pixel row of Pt (76 words)
constexpr int HT_STRIDE = 272;  // bytes/pixel row of Ht
constexpr int NT  = 256;

// pixel-major padded bf16 x: [b][h' 0..33][w' 0..33][mc 0..1023]
constexpr size_t XPM_SLABS = 34 * 34;                       // per b
constexpr size_t XPM_B     = XPM_SLABS * MCn;               // ushorts per b
constexpr size_t XPM_BYTES = (size_t)Bn * XPM_B * 2;        // 37,879,808
constexpr size_t W1_ELEMS  = (size_t)Mn * Hd * K9;          // 1,179,648
constexpr size_t W2_ELEMS  = (size_t)Mn * Cn * Hd;          // 131,072
constexpr size_t WS_NEED   = XPM_BYTES + 2 * (W1_ELEMS + W2_ELEMS);

__device__ __forceinline__ ushort f2bf(float f) {
    return __bfloat16_as_ushort(__float2bfloat16(f));
}
__device__ __forceinline__ float bf2f(ushort u) {
    union { uint i; float f; } v; v.i = (uint)u << 16; return v.f;
}

// ---------------------------------------------------------------------------
// prep: x [b][mc][32][32] f32 -> xpm [b][h+1][w+1][mc] bf16 (interior only)
// block = (b, h, ck): one 256-mc chunk of one (b,h) row-slab set
// ---------------------------------------------------------------------------
__global__ __launch_bounds__(256)
void prep_xpm(const float* __restrict__ x, ushort* __restrict__ xpm)
{
    const int bid = blockIdx.x;
    const int b  = bid >> 7;
    const int h  = (bid >> 2) & 31;
    const int ck = bid & 3;
    const int tid = threadIdx.x;

    __shared__ ushort T[256][36];   // [mc_local][w], padded

    // read: thread = one mc row (32 floats contiguous)
    const int mc = ck * 256 + tid;
    const float* src = x + (((size_t)b * MCn + mc) * 32 + h) * 32;
    #pragma unroll
    for (int j = 0; j < 8; ++j) {
        const float4 f = *(const float4*)(src + 4 * j);
        uint2 pk;
        pk.x = (uint)f2bf(f.x) | ((uint)f2bf(f.y) << 16);
        pk.y = (uint)f2bf(f.z) | ((uint)f2bf(f.w) << 16);
        *(uint2*)&T[tid][4 * j] = pk;
    }
    __syncthreads();

    // write: 4 reps x 256 threads cover 256 mc x 32 w.
    // rep r: thread -> (q8 = tid&31 -> mc group of 8, w = (tid>>5) + 8r).
    // consecutive tids at fixed w write contiguous 16B chunks (coalesced).
    ushort* const dstb = xpm + (size_t)b * XPM_B + ((size_t)(h + 1) * 34) * MCn
                       + ck * 256;
    #pragma unroll
    for (int rep = 0; rep < 4; ++rep) {
        const int q8 = tid & 31;               // mc_local group (8 channels)
        const int w  = (tid >> 5) + 8 * rep;   // pixel column
        ushort tmp[8];
        #pragma unroll
        for (int k2 = 0; k2 < 8; ++k2) tmp[k2] = T[8 * q8 + k2][w];
        uint4 v;
        v.x = (uint)tmp[0] | ((uint)tmp[1] << 16);
        v.y = (uint)tmp[2] | ((uint)tmp[3] << 16);
        v.z = (uint)tmp[4] | ((uint)tmp[5] << 16);
        v.w = (uint)tmp[6] | ((uint)tmp[7] << 16);
        *(uint4*)(dstb + (size_t)(w + 1) * MCn + 8 * q8) = v;
    }
}

// zero the border slabs/columns of xpm: per b, 132 (h',w') positions x 2KB
__global__ __launch_bounds__(128)
void prep_border(ushort* __restrict__ xpm)
{
    const int bp  = blockIdx.x;
    const int b   = bp / 132;
    const int pos = bp % 132;
    int hh, ww;
    if      (pos < 34)  { hh = 0;              ww = pos;        }
    else if (pos < 68)  { hh = 33;             ww = pos - 34;   }
    else if (pos < 100) { hh = pos - 68 + 1;   ww = 0;          }
    else                { hh = pos - 100 + 1;  ww = 33;         }
    ushort* dst = xpm + (size_t)b * XPM_B + ((size_t)hh * 34 + ww) * MCn
                + threadIdx.x * 8;
    *(uint4*)dst = (uint4){0, 0, 0, 0};
}

// weights f32 -> bf16
__global__ __launch_bounds__(256)
void prep_w(const float* __restrict__ w1, const float* __restrict__ w2,
            ushort* __restrict__ w1bf, ushort* __restrict__ w2bf)
{
    const size_t i = ((size_t)blockIdx.x * 256 + threadIdx.x) * 4;
    const float* src; ushort* dst; size_t e;
    if (i < W1_ELEMS) { src = w1; dst = w1bf; e = i; }
    else              { src = w2; dst = w2bf; e = i - W1_ELEMS; }
    const float4 f = *(const float4*)(src + e);
    uint2 pk;
    pk.x = (uint)f2bf(f.x) | ((uint)f2bf(f.y) << 16);
    pk.y = (uint)f2bf(f.z) | ((uint)f2bf(f.w) << 16);
    *(uint2*)(dst + e) = pk;
}

// ---------------------------------------------------------------------------
// main kernel (pixel-major bf16 source; never touches f32 x)
// ---------------------------------------------------------------------------
__global__ __launch_bounds__(NT, 4)
void nca_mfma_pm(const ushort* __restrict__ xpm,
                 const ushort* __restrict__ w1bf, const float* __restrict__ b1,
                 const ushort* __restrict__ w2bf, const float* __restrict__ b2,
                 float* __restrict__ out)
{
    // union: Pt[p][k] bf16 perception; then Ht[p][hd] bf16 hidden; then dxT f32.
    __shared__ __align__(16) char U[NP * PT_STRIDE + 16];
    char* const PtL = U;
    char* const HtL = U;

    const int tid  = threadIdx.x;
    const int lane = tid & 63;
    const int wid  = tid >> 6;      // wave 0..3
    const int lr   = lane & 15;     // MFMA row/col lane index
    const int lk   = lane >> 4;     // MFMA k-group 0..3

    // XCD-group swizzle (round 4: kept)
    const int bid = blockIdx.x;
    const int xcd = bid & 7;
    const int jb  = bid >> 3;
    const int m   = jb & 63;                // model 0..63
    const int g   = (jb >> 6) * 8 + xcd;    // pixel group 0..127
    const int b   = g >> 3;                 // batch 0..15
    const int p0  = (g & 7) * NP;           // pixel base within image

    const ushort* const xpb = xpm + (size_t)b * XPM_B;

    // zero k-pad columns [288,304) + guard row
    if (tid <= NP) {
        char* z = PtL + tid * PT_STRIDE + (tid < NP ? 288 : 0);
        *(int4*)z = (int4){0, 0, 0, 0};
    }

    // ---------- w1 bf16 A-frags ----------
    short8 a1[2][5];
    #pragma unroll
    for (int rt = 0; rt < 2; ++rt) {
        const int row = wid * 32 + rt * 16 + lr;
        const ushort* wr = w1bf + (m * Hd + row) * K9;
        #pragma unroll
        for (int ks = 0; ks < 5; ++ks) {
            const int k0 = ks * 32 + lk * 8;
            a1[rt][ks] = (k0 < K9) ? *(const short8*)(wr + k0)
                                   : (short8){0,0,0,0,0,0,0,0};
        }
    }
    // ---------- w2 bf16 A-frags ----------
    short8 a2[4];
    #pragma unroll
    for (int ks = 0; ks < 4; ++ks)
        a2[ks] = *(const short8*)(w2bf + (m * Cn + lr) * Hd + ks * 32 + lk * 8);

    // ---------- gather: xpm -> Pt (two contiguous runs per pixel row) ----------
    // window [144m, 144m+144): run0 = shift s0 channels [mc0, mc0+len0),
    // run1 = shift s0+1 channels [0, 144-len0). Boundaries mult of 16 ch;
    // 8-ch chunks never straddle (len0 mult of 16, ko mult of 8).
    {
        const unsigned long long TAB = 0xA62918405ull;  // (dr+1)|((dc+1)<<2)
        const int ch0  = m * K9;
        const int s0g  = ch0 >> 10;
        const int mc0  = ch0 & 1023;
        const int len0 = min(K9, 1024 - mc0);
        const uint nib0 = (uint)(TAB >> (4 * s0g)) & 15u;
        const uint nib1 = (uint)(TAB >> (4 * (s0g + 1))) & 15u;
        const int dr0 = (int)(nib0 & 3u) - 1, dc0 = (int)(nib0 >> 2) - 1;
        const int dr1 = (int)(nib1 & 3u) - 1, dc1 = (int)(nib1 >> 2) - 1;

        const int p   = tid >> 1;
        const int c0c = (tid & 1) * 72;         // half-row: ch [c0c, c0c+72)
        const int gp  = p0 + p;
        const int h   = gp >> 5, w = gp & 31;
        const ushort* src0 = xpb + ((h + dr0 + 1) * 34 + (w + dc0 + 1)) * MCn + mc0;
        const ushort* src1 = xpb + ((h + dr1 + 1) * 34 + (w + dc1 + 1)) * MCn;
        char* const dstb = PtL + p * PT_STRIDE + c0c * 2;

        #pragma unroll
        for (int i = 0; i < 9; ++i) {
            const int ko = c0c + 8 * i;         // mult of 8 ch = 16B units
            const ushort* s = (ko < len0) ? (src0 + ko) : (src1 + (ko - len0));
            *(uint4*)(dstb + 16 * i) = *(const uint4*)s;
        }
    }
    __syncthreads();

    // ---------- GEMM1: hdn = w1 @ P, 128x128x160 ----------
    f32x4 acc[2][8];
    #pragma unroll
    for (int i = 0; i < 2; ++i)
        #pragma unroll
        for (int jj = 0; jj < 8; ++jj) acc[i][jj] = (f32x4){0.f, 0.f, 0.f, 0.f};

    #pragma unroll
    for (int ct = 0; ct < 8; ++ct) {
        const int p = ct * 16 + lr;
        const char* base = PtL + p * PT_STRIDE + lk * 16;
        short8 bfrag[5];
        #pragma unroll
        for (int ks = 0; ks < 5; ++ks)
            bfrag[ks] = *(const short8*)(base + ks * 64);
        #pragma unroll
        for (int ks = 0; ks < 5; ++ks) {
            acc[0][ct] = __builtin_amdgcn_mfma_f32_16x16x32_bf16(a1[0][ks], bfrag[ks], acc[0][ct], 0, 0, 0);
            acc[1][ct] = __builtin_amdgcn_mfma_f32_16x16x32_bf16(a1[1][ks], bfrag[ks], acc[1][ct], 0, 0, 0);
        }
    }
    __syncthreads();   // Pt reads done -> reuse U as Ht

    // ---------- bias+relu -> Ht[p][hd] bf16 ----------
    #pragma unroll
    for (int rt = 0; rt < 2; ++rt) {
        const int hd0 = wid * 32 + rt * 16 + lk * 4;   // C/D row = (lane>>4)*4 + reg
        const float4 bs = *(const float4*)(b1 + m * Hd + hd0);
        #pragma unroll
        for (int ct = 0; ct < 8; ++ct) {
            const int p = ct * 16 + lr;                // C/D col = lane&15
            const f32x4 v = acc[rt][ct];
            uint2 pk;
            pk.x = (uint)f2bf(fmaxf(v[0] + bs.x, 0.f)) |
                   ((uint)f2bf(fmaxf(v[1] + bs.y, 0.f)) << 16);
            pk.y = (uint)f2bf(fmaxf(v[2] + bs.z, 0.f)) |
                   ((uint)f2bf(fmaxf(v[3] + bs.w, 0.f)) << 16);
            *(uint2*)(HtL + p * HT_STRIDE + hd0 * 2) = pk;
        }
    }
    __syncthreads();

    // ---------- GEMM2: dx = w2 @ hdn, 16x128x128 ----------
    f32x4 acc2[2];
    #pragma unroll
    for (int jj = 0; jj < 2; ++jj) {
        const int ct = wid * 2 + jj;
        const int p  = ct * 16 + lr;
        const char* base = HtL + p * HT_STRIDE + lk * 16;
        short8 bb[4];
        #pragma unroll
        for (int ks = 0; ks < 4; ++ks)
            bb[ks] = *(const short8*)(base + ks * 64);
        f32x4 a = (f32x4){0.f, 0.f, 0.f, 0.f};
        #pragma unroll
        for (int ks = 0; ks < 4; ++ks)
            a = __builtin_amdgcn_mfma_f32_16x16x32_bf16(a2[ks], bb[ks], a, 0, 0, 0);
        acc2[jj] = a;
    }
    __syncthreads();   // Ht reads done -> reuse U as dxT

    // ---------- epilogue: residual(bf16 xpm) + bias -> dxT -> 512B out writes ----
    const float4 b2v = *(const float4*)(b2 + m * Cn + lk * 4);
    float (*dxT)[132] = (float(*)[132])U;   // 16 x 132 f32
    {
        const float bsv[4] = {b2v.x, b2v.y, b2v.z, b2v.w};
        #pragma unroll
        for (int jj = 0; jj < 2; ++jj) {
            const int px = (wid * 2 + jj) * 16 + lr;
            const int gp = p0 + px;
            const int h  = gp >> 5, w = gp & 31;
            const ushort* res = xpb + ((h + 1) * 34 + (w + 1)) * MCn + m * Cn + lk * 4;
            #pragma unroll
            for (int rr2 = 0; rr2 < 4; ++rr2)
                dxT[lk * 4 + rr2][px] = acc2[jj][rr2] + bsv[rr2] + bf2f(res[rr2]);
        }
    }
    __syncthreads();
    {
        const int c = tid >> 4, iq = tid & 15;
        const int px0 = 8 * iq;
        const float4 d0 = *(const float4*)&dxT[c][px0];
        const float4 d1 = *(const float4*)&dxT[c][px0 + 4];
        const size_t idx = ((size_t)(b * MCn + m * Cn + c)) * 1024 + p0 + px0;
        *(float4*)(out + idx)     = d0;
        *(float4*)(out + idx + 4) = d1;
    }
}

// ---------------------------------------------------------------------------
// fallback (f32-direct, round 6): used when ws_size < WS_NEED
// ---------------------------------------------------------------------------
__global__ __launch_bounds__(NT, 4)
void nca_mfma_f32src(const float* __restrict__ x,  const float* __restrict__ w1,
                     const float* __restrict__ b1, const float* __restrict__ w2,
                     const float* __restrict__ b2, float* __restrict__ out)
{
    __shared__ __align__(16) char U[NP * PT_STRIDE + 16];
    char* const PtL = U;
    char* const HtL = U;

    const int tid  = threadIdx.x;
    const int lane = tid & 63;
    const int wid  = tid >> 6;
    const int lr   = lane & 15;
    const int lk   = lane >> 4;

    const int bid = blockIdx.x;
    const int xcd = bid & 7;
    const int jb  = bid >> 3;
    const int m   = jb & 63;
    const int g   = (jb >> 6) * 8 + xcd;
    const int b   = g >> 3;
    const int p0  = (g & 7) * NP;

    if (tid <= NP) {
        char* z = PtL + tid * PT_STRIDE + (tid < NP ? 288 : 0);
        *(int4*)z = (int4){0, 0, 0, 0};
    }

    short8 a1[2][5];
    #pragma unroll
    for (int rt = 0; rt < 2; ++rt) {
        const int row = wid * 32 + rt * 16 + lr;
        const float* wr = w1 + (m * Hd + row) * K9;
        #pragma unroll
        for (int ks = 0; ks < 5; ++ks) {
            const int k0 = ks * 32 + lk * 8;
            short8 t;
            if (k0 < K9) {
                const float4 f0 = *(const float4*)(wr + k0);
                const float4 f1 = *(const float4*)(wr + k0 + 4);
                t[0] = (short)f2bf(f0.x); t[1] = (short)f2bf(f0.y);
                t[2] = (short)f2bf(f0.z); t[3] = (short)f2bf(f0.w);
                t[4] = (short)f2bf(f1.x); t[5] = (short)f2bf(f1.y);
                t[6] = (short)f2bf(f1.z); t[7] = (short)f2bf(f1.w);
            } else t = (short8){0,0,0,0,0,0,0,0};
            a1[rt][ks] = t;
        }
    }
    short8 a2[4];
    #pragma unroll
    for (int ks = 0; ks < 4; ++ks) {
        const float* wr = w2 + (m * Cn + lr) * Hd + ks * 32 + lk * 8;
        const float4 f0 = *(const float4*)(wr);
        const float4 f1 = *(const float4*)(wr + 4);
        short8 t;
        t[0] = (short)f2bf(f0.x); t[1] = (short)f2bf(f0.y);
        t[2] = (short)f2bf(f0.z); t[3] = (short)f2bf(f0.w);
        t[4] = (short)f2bf(f1.x); t[5] = (short)f2bf(f1.y);
        t[6] = (short)f2bf(f1.z); t[7] = (short)f2bf(f1.w);
        a2[ks] = t;
    }
    {
        const int s     = tid & 7;
        const int kpl   = (tid >> 3) & 7;
        const int r     = tid >> 6;
        const int rbase = (g & 7) * 4 + r;
        const float* xb = x + (size_t)b * (MCn * 1024);
        const unsigned long long TAB = 0xA62918405ull;
        #pragma unroll
        for (int it = 0; it < 9; ++it) {
            const int kp = it * 8 + kpl;
            float4 hv[2];
            #pragma unroll
            for (int half = 0; half < 2; ++half) {
                const int ch = m * K9 + kp * 2 + half;
                const int sh = ch >> 10;
                const int mc = ch & 1023;
                const uint nib = (uint)(TAB >> (4 * sh)) & 15u;
                const int dr = (int)(nib & 3u) - 1;
                const int dc = (int)(nib >> 2) - 1;
                const int row = rbase + dr;
                const int wb  = 4 * s + dc;
                const int wc  = min(max(wb, 0), 28);
                float4 f = {0.f, 0.f, 0.f, 0.f};
                if ((unsigned)row < 32u)
                    f = *(const float4*)(xb + (mc * 32 + row) * 32 + wc);
                if (wb < 0)       { f.w = f.z; f.z = f.y; f.y = f.x; f.x = 0.f; }
                else if (wb > 28) { f.x = f.y; f.y = f.z; f.z = f.w; f.w = 0.f; }
                hv[half] = f;
            }
            char* dst = PtL + (r * 32 + 4 * s) * PT_STRIDE + kp * 4;
            *(uint*)(dst)                 = (uint)f2bf(hv[0].x) | ((uint)f2bf(hv[1].x) << 16);
            *(uint*)(dst + PT_STRIDE)     = (uint)f2bf(hv[0].y) | ((uint)f2bf(hv[1].y) << 16);
            *(uint*)(dst + 2 * PT_STRIDE) = (uint)f2bf(hv[0].z) | ((uint)f2bf(hv[1].z) << 16);
            *(uint*)(dst + 3 * PT_STRIDE) = (uint)f2bf(hv[0].w) | ((uint)f2bf(hv[1].w) << 16);
        }
    }
    __syncthreads();

    f32x4 acc[2][8];
    #pragma unroll
    for (int i = 0; i < 2; ++i)
        #pragma unroll
        for (int jj = 0; jj < 8; ++jj) acc[i][jj] = (f32x4){0.f, 0.f, 0.f, 0.f};
    #pragma unroll
    for (int ct = 0; ct < 8; ++ct) {
        const int p = ct * 16 + lr;
        const char* base = PtL + p * PT_STRIDE + lk * 16;
        short8 bfrag[5];
        #pragma unroll
        for (int ks = 0; ks < 5; ++ks)
            bfrag[ks] = *(const short8*)(base + ks * 64);
        #pragma unroll
        for (int ks = 0; ks < 5; ++ks) {
            acc[0][ct] = __builtin_amdgcn_mfma_f32_16x16x32_bf16(a1[0][ks], bfrag[ks], acc[0][ct], 0, 0, 0);
            acc[1][ct] = __builtin_amdgcn_mfma_f32_16x16x32_bf16(a1[1][ks], bfrag[ks], acc[1][ct], 0, 0, 0);
        }
    }
    __syncthreads();
    #pragma unroll
    for (int rt = 0; rt < 2; ++rt) {
        const int hd0 = wid * 32 + rt * 16 + lk * 4;
        const float4 bs = *(const float4*)(b1 + m * Hd + hd0);
        #pragma unroll
        for (int ct = 0; ct < 8; ++ct) {
            const int p = ct * 16 + lr;
            const f32x4 v = acc[rt][ct];
            uint2 pk;
            pk.x = (uint)f2bf(fmaxf(v[0] + bs.x, 0.f)) |
                   ((uint)f2bf(fmaxf(v[1] + bs.y, 0.f)) << 16);
            pk.y = (uint)f2bf(fmaxf(v[2] + bs.z, 0.f)) |
                   ((uint)f2bf(fmaxf(v[3] + bs.w, 0.f)) << 16);
            *(uint2*)(HtL + p * HT_STRIDE + hd0 * 2) = pk;
        }
    }
    __syncthreads();
    f32x4 acc2[2];
    #pragma unroll
    for (int jj = 0; jj < 2; ++jj) {
        const int ct = wid * 2 + jj;
        const int p  = ct * 16 + lr;
        const char* base = HtL + p * HT_STRIDE + lk * 16;
        short8 bb[4];
        #pragma unroll
        for (int ks = 0; ks < 4; ++ks)
            bb[ks] = *(const short8*)(base + ks * 64);
        f32x4 a = (f32x4){0.f, 0.f, 0.f, 0.f};
        #pragma unroll
        for (int ks = 0; ks < 4; ++ks)
            a = __builtin_amdgcn_mfma_f32_16x16x32_bf16(a2[ks], bb[ks], a, 0, 0, 0);
        acc2[jj] = a;
    }
    const float4 b2v = *(const float4*)(b2 + m * Cn + lk * 4);
    const float bsv[4] = {b2v.x, b2v.y, b2v.z, b2v.w};
    #pragma unroll
    for (int jj = 0; jj < 2; ++jj) {
        const int ct = wid * 2 + jj;
        const int gp = p0 + ct * 16 + lr;
        #pragma unroll
        for (int r = 0; r < 4; ++r) {
            const int c   = lk * 4 + r;
            const size_t idx = ((size_t)(b * MCn + m * Cn + c)) * 1024 + gp;
            out[idx] = x[idx] + acc2[jj][r] + bsv[r];
        }
    }
}

extern "C" void kernel_launch(void* const* d_in, const int* in_sizes, int n_in,
                              void* d_out, int out_size, void* d_ws, size_t ws_size,
                              hipStream_t stream)
{
    const float* x  = (const float*)d_in[0];
    const float* w1 = (const float*)d_in[1];
    const float* b1 = (const float*)d_in[2];
    const float* w2 = (const float*)d_in[3];
    const float* b2 = (const float*)d_in[4];
    float* out = (float*)d_out;
    const int grid = Mn * (Bn * 1024 / NP);   // 8192

    if (ws_size >= WS_NEED) {
        ushort* xpm  = (ushort*)d_ws;
        ushort* w1bf = (ushort*)((char*)d_ws + XPM_BYTES);
        ushort* w2bf = w1bf + W1_ELEMS;
        prep_xpm<<<Bn * 32 * 4, 256, 0, stream>>>(x, xpm);
        prep_border<<<Bn * 132, 128, 0, stream>>>(xpm);
        prep_w<<<(int)((W1_ELEMS + W2_ELEMS) / 4 / 256), 256, 0, stream>>>(w1, w2, w1bf, w2bf);
        nca_mfma_pm<<<grid, NT, 0, stream>>>(xpm, w1bf, b1, w2bf, b2, out);
    } else {
        nca_mfma_f32src<<<grid, NT, 0, stream>>>(x, w1, b1, w2, b2, out);
    }
}

// Round 12
// 143.171 us; speedup vs baseline: 1.1698x; 1.0549x over previous
//
#include <hip/hip_runtime.h>
#include <hip/hip_bf16.h>

// ParallelNCA on MFMA: 64 grouped MLPs (144->128->16) over 3x3 perception.
// Round 11 = round 10 + two-level dispatch tiling per XCD:
//   (m-chunk of 32) OUTER x (group) MID x (m within chunk) FAST.
//   Weight re-touch distance 32 blocks (churn ~1.7MB < 4MB L2) -> each chunk's
//   1.26MB weights stay L2-resident across all 16 groups; xpm re-read 2x.
//   Pure bijective index remap; all compute phases identical to round 10.

typedef __attribute__((ext_vector_type(8))) short short8;   // 8 bf16 frag
typedef __attribute__((ext_vector_type(4))) float f32x4;    // MFMA acc

constexpr int Bn  = 16;
constexpr int Mn  = 64;
constexpr int Cn  = 16;
constexpr int Hd  = 128;
constexpr int K9  = 144;
constexpr int MCn = 1024;
constexpr int NP  = 128;        // pixels per block (4 image rows)
constexpr int PT_STRIDE = 304;  // bytes/pixel row of Pt (76 words)
constexpr int HT_STRIDE = 272;  // bytes/pixel row of Ht
constexpr int NT  = 256;

// pixel-major padded bf16 x: [b][h' 0..33][w' 0..33][mc 0..1023]
constexpr size_t XPM_SLABS = 34 * 34;                       // per b
constexpr size_t XPM_B     = XPM_SLABS * MCn;               // ushorts per b
constexpr size_t XPM_BYTES = (size_t)Bn * XPM_B * 2;        // 37,879,808
constexpr size_t W1_ELEMS  = (size_t)Mn * Hd * K9;          // 1,179,648
constexpr size_t W2_ELEMS  = (size_t)Mn * Cn * Hd;          // 131,072
constexpr size_t WS_NEED   = XPM_BYTES + 2 * (W1_ELEMS + W2_ELEMS);

__device__ __forceinline__ ushort f2bf(float f) {
    return __bfloat16_as_ushort(__float2bfloat16(f));
}
__device__ __forceinline__ float bf2f(ushort u) {
    union { uint i; float f; } v; v.i = (uint)u << 16; return v.f;
}

// ---------------------------------------------------------------------------
// prep: x [b][mc][32][32] f32 -> xpm [b][h+1][w+1][mc] bf16 (interior only)
// ---------------------------------------------------------------------------
__global__ __launch_bounds__(256)
void prep_xpm(const float* __restrict__ x, ushort* __restrict__ xpm)
{
    const int bid = blockIdx.x;
    const int b  = bid >> 7;
    const int h  = (bid >> 2) & 31;
    const int ck = bid & 3;
    const int tid = threadIdx.x;

    __shared__ ushort T[256][36];   // [mc_local][w], padded

    const int mc = ck * 256 + tid;
    const float* src = x + (((size_t)b * MCn + mc) * 32 + h) * 32;
    #pragma unroll
    for (int j = 0; j < 8; ++j) {
        const float4 f = *(const float4*)(src + 4 * j);
        uint2 pk;
        pk.x = (uint)f2bf(f.x) | ((uint)f2bf(f.y) << 16);
        pk.y = (uint)f2bf(f.z) | ((uint)f2bf(f.w) << 16);
        *(uint2*)&T[tid][4 * j] = pk;
    }
    __syncthreads();

    // write: 4 reps x 256 threads cover 256 mc x 32 w (coalesced 16B chunks)
    ushort* const dstb = xpm + (size_t)b * XPM_B + ((size_t)(h + 1) * 34) * MCn
                       + ck * 256;
    #pragma unroll
    for (int rep = 0; rep < 4; ++rep) {
        const int q8 = tid & 31;               // mc_local group (8 channels)
        const int w  = (tid >> 5) + 8 * rep;   // pixel column
        ushort tmp[8];
        #pragma unroll
        for (int k2 = 0; k2 < 8; ++k2) tmp[k2] = T[8 * q8 + k2][w];
        uint4 v;
        v.x = (uint)tmp[0] | ((uint)tmp[1] << 16);
        v.y = (uint)tmp[2] | ((uint)tmp[3] << 16);
        v.z = (uint)tmp[4] | ((uint)tmp[5] << 16);
        v.w = (uint)tmp[6] | ((uint)tmp[7] << 16);
        *(uint4*)(dstb + (size_t)(w + 1) * MCn + 8 * q8) = v;
    }
}

// zero the border slabs/columns of xpm: per b, 132 (h',w') positions x 2KB
__global__ __launch_bounds__(128)
void prep_border(ushort* __restrict__ xpm)
{
    const int bp  = blockIdx.x;
    const int b   = bp / 132;
    const int pos = bp % 132;
    int hh, ww;
    if      (pos < 34)  { hh = 0;              ww = pos;        }
    else if (pos < 68)  { hh = 33;             ww = pos - 34;   }
    else if (pos < 100) { hh = pos - 68 + 1;   ww = 0;          }
    else                { hh = pos - 100 + 1;  ww = 33;         }
    ushort* dst = xpm + (size_t)b * XPM_B + ((size_t)hh * 34 + ww) * MCn
                + threadIdx.x * 8;
    *(uint4*)dst = (uint4){0, 0, 0, 0};
}

// weights f32 -> bf16
__global__ __launch_bounds__(256)
void prep_w(const float* __restrict__ w1, const float* __restrict__ w2,
            ushort* __restrict__ w1bf, ushort* __restrict__ w2bf)
{
    const size_t i = ((size_t)blockIdx.x * 256 + threadIdx.x) * 4;
    const float* src; ushort* dst; size_t e;
    if (i < W1_ELEMS) { src = w1; dst = w1bf; e = i; }
    else              { src = w2; dst = w2bf; e = i - W1_ELEMS; }
    const float4 f = *(const float4*)(src + e);
    uint2 pk;
    pk.x = (uint)f2bf(f.x) | ((uint)f2bf(f.y) << 16);
    pk.y = (uint)f2bf(f.z) | ((uint)f2bf(f.w) << 16);
    *(uint2*)(dst + e) = pk;
}

// ---------------------------------------------------------------------------
// main kernel (pixel-major bf16 source; never touches f32 x)
// ---------------------------------------------------------------------------
__global__ __launch_bounds__(NT, 4)
void nca_mfma_pm(const ushort* __restrict__ xpm,
                 const ushort* __restrict__ w1bf, const float* __restrict__ b1,
                 const ushort* __restrict__ w2bf, const float* __restrict__ b2,
                 float* __restrict__ out)
{
    // union: Pt[p][k] bf16 perception; then Ht[p][hd] bf16 hidden; then dxT f32.
    __shared__ __align__(16) char U[NP * PT_STRIDE + 16];
    char* const PtL = U;
    char* const HtL = U;

    const int tid  = threadIdx.x;
    const int lane = tid & 63;
    const int wid  = tid >> 6;      // wave 0..3
    const int lr   = lane & 15;     // MFMA row/col lane index
    const int lk   = lane >> 4;     // MFMA k-group 0..3

    // two-level dispatch tiling per XCD (round 11):
    //   j = bid>>3: mlo = j&31 (fast), glo = (j>>5)&15 (mid), mch = j>>9 (slow)
    const int bid = blockIdx.x;
    const int xcd = bid & 7;
    const int j   = bid >> 3;               // 0..1023
    const int mlo = j & 31;
    const int glo = (j >> 5) & 15;
    const int mch = j >> 9;                 // 0..1
    const int m   = mch * 32 + mlo;         // model 0..63
    const int g   = glo * 8 + xcd;          // pixel group 0..127
    const int b   = g >> 3;                 // batch 0..15
    const int p0  = (g & 7) * NP;           // pixel base within image

    const ushort* const xpb = xpm + (size_t)b * XPM_B;

    // zero k-pad columns [288,304) + guard row
    if (tid <= NP) {
        char* z = PtL + tid * PT_STRIDE + (tid < NP ? 288 : 0);
        *(int4*)z = (int4){0, 0, 0, 0};
    }

    // ---------- w1 bf16 A-frags ----------
    short8 a1[2][5];
    #pragma unroll
    for (int rt = 0; rt < 2; ++rt) {
        const int row = wid * 32 + rt * 16 + lr;
        const ushort* wr = w1bf + (m * Hd + row) * K9;
        #pragma unroll
        for (int ks = 0; ks < 5; ++ks) {
            const int k0 = ks * 32 + lk * 8;
            a1[rt][ks] = (k0 < K9) ? *(const short8*)(wr + k0)
                                   : (short8){0,0,0,0,0,0,0,0};
        }
    }
    // ---------- w2 bf16 A-frags ----------
    short8 a2[4];
    #pragma unroll
    for (int ks = 0; ks < 4; ++ks)
        a2[ks] = *(const short8*)(w2bf + (m * Cn + lr) * Hd + ks * 32 + lk * 8);

    // ---------- gather: xpm -> Pt (two contiguous runs per pixel row) ----------
    {
        const unsigned long long TAB = 0xA62918405ull;  // (dr+1)|((dc+1)<<2)
        const int ch0  = m * K9;
        const int s0g  = ch0 >> 10;
        const int mc0  = ch0 & 1023;
        const int len0 = min(K9, 1024 - mc0);
        const uint nib0 = (uint)(TAB >> (4 * s0g)) & 15u;
        const uint nib1 = (uint)(TAB >> (4 * (s0g + 1))) & 15u;
        const int dr0 = (int)(nib0 & 3u) - 1, dc0 = (int)(nib0 >> 2) - 1;
        const int dr1 = (int)(nib1 & 3u) - 1, dc1 = (int)(nib1 >> 2) - 1;

        const int p   = tid >> 1;
        const int c0c = (tid & 1) * 72;         // half-row: ch [c0c, c0c+72)
        const int gp  = p0 + p;
        const int h   = gp >> 5, w = gp & 31;
        const ushort* src0 = xpb + ((h + dr0 + 1) * 34 + (w + dc0 + 1)) * MCn + mc0;
        const ushort* src1 = xpb + ((h + dr1 + 1) * 34 + (w + dc1 + 1)) * MCn;
        char* const dstb = PtL + p * PT_STRIDE + c0c * 2;

        #pragma unroll
        for (int i = 0; i < 9; ++i) {
            const int ko = c0c + 8 * i;         // mult of 8 ch = 16B units
            const ushort* s = (ko < len0) ? (src0 + ko) : (src1 + (ko - len0));
            *(uint4*)(dstb + 16 * i) = *(const uint4*)s;
        }
    }
    __syncthreads();

    // ---------- GEMM1: hdn = w1 @ P, 128x128x160 ----------
    f32x4 acc[2][8];
    #pragma unroll
    for (int i = 0; i < 2; ++i)
        #pragma unroll
        for (int jj = 0; jj < 8; ++jj) acc[i][jj] = (f32x4){0.f, 0.f, 0.f, 0.f};

    #pragma unroll
    for (int ct = 0; ct < 8; ++ct) {
        const int p = ct * 16 + lr;
        const char* base = PtL + p * PT_STRIDE + lk * 16;
        short8 bfrag[5];
        #pragma unroll
        for (int ks = 0; ks < 5; ++ks)
            bfrag[ks] = *(const short8*)(base + ks * 64);
        #pragma unroll
        for (int ks = 0; ks < 5; ++ks) {
            acc[0][ct] = __builtin_amdgcn_mfma_f32_16x16x32_bf16(a1[0][ks], bfrag[ks], acc[0][ct], 0, 0, 0);
            acc[1][ct] = __builtin_amdgcn_mfma_f32_16x16x32_bf16(a1[1][ks], bfrag[ks], acc[1][ct], 0, 0, 0);
        }
    }
    __syncthreads();   // Pt reads done -> reuse U as Ht

    // ---------- bias+relu -> Ht[p][hd] bf16 ----------
    #pragma unroll
    for (int rt = 0; rt < 2; ++rt) {
        const int hd0 = wid * 32 + rt * 16 + lk * 4;   // C/D row = (lane>>4)*4 + reg
        const float4 bs = *(const float4*)(b1 + m * Hd + hd0);
        #pragma unroll
        for (int ct = 0; ct < 8; ++ct) {
            const int p = ct * 16 + lr;                // C/D col = lane&15
            const f32x4 v = acc[rt][ct];
            uint2 pk;
            pk.x = (uint)f2bf(fmaxf(v[0] + bs.x, 0.f)) |
                   ((uint)f2bf(fmaxf(v[1] + bs.y, 0.f)) << 16);
            pk.y = (uint)f2bf(fmaxf(v[2] + bs.z, 0.f)) |
                   ((uint)f2bf(fmaxf(v[3] + bs.w, 0.f)) << 16);
            *(uint2*)(HtL + p * HT_STRIDE + hd0 * 2) = pk;
        }
    }
    __syncthreads();

    // ---------- GEMM2: dx = w2 @ hdn, 16x128x128 ----------
    f32x4 acc2[2];
    #pragma unroll
    for (int jj = 0; jj < 2; ++jj) {
        const int ct = wid * 2 + jj;
        const int p  = ct * 16 + lr;
        const char* base = HtL + p * HT_STRIDE + lk * 16;
        short8 bb[4];
        #pragma unroll
        for (int ks = 0; ks < 4; ++ks)
            bb[ks] = *(const short8*)(base + ks * 64);
        f32x4 a = (f32x4){0.f, 0.f, 0.f, 0.f};
        #pragma unroll
        for (int ks = 0; ks < 4; ++ks)
            a = __builtin_amdgcn_mfma_f32_16x16x32_bf16(a2[ks], bb[ks], a, 0, 0, 0);
        acc2[jj] = a;
    }
    __syncthreads();   // Ht reads done -> reuse U as dxT

    // ---------- epilogue: residual(bf16 xpm) + bias -> dxT -> 512B out writes ----
    const float4 b2v = *(const float4*)(b2 + m * Cn + lk * 4);
    float (*dxT)[132] = (float(*)[132])U;   // 16 x 132 f32
    {
        const float bsv[4] = {b2v.x, b2v.y, b2v.z, b2v.w};
        #pragma unroll
        for (int jj = 0; jj < 2; ++jj) {
            const int px = (wid * 2 + jj) * 16 + lr;
            const int gp = p0 + px;
            const int h  = gp >> 5, w = gp & 31;
            const ushort* res = xpb + ((h + 1) * 34 + (w + 1)) * MCn + m * Cn + lk * 4;
            #pragma unroll
            for (int rr2 = 0; rr2 < 4; ++rr2)
                dxT[lk * 4 + rr2][px] = acc2[jj][rr2] + bsv[rr2] + bf2f(res[rr2]);
        }
    }
    __syncthreads();
    {
        const int c = tid >> 4, iq = tid & 15;
        const int px0 = 8 * iq;
        const float4 d0 = *(const float4*)&dxT[c][px0];
        const float4 d1 = *(const float4*)&dxT[c][px0 + 4];
        const size_t idx = ((size_t)(b * MCn + m * Cn + c)) * 1024 + p0 + px0;
        *(float4*)(out + idx)     = d0;
        *(float4*)(out + idx + 4) = d1;
    }
}

// ---------------------------------------------------------------------------
// fallback (f32-direct, round 6): used when ws_size < WS_NEED
// ---------------------------------------------------------------------------
__global__ __launch_bounds__(NT, 4)
void nca_mfma_f32src(const float* __restrict__ x,  const float* __restrict__ w1,
                     const float* __restrict__ b1, const float* __restrict__ w2,
                     const float* __restrict__ b2, float* __restrict__ out)
{
    __shared__ __align__(16) char U[NP * PT_STRIDE + 16];
    char* const PtL = U;
    char* const HtL = U;

    const int tid  = threadIdx.x;
    const int lane = tid & 63;
    const int wid  = tid >> 6;
    const int lr   = lane & 15;
    const int lk   = lane >> 4;

    const int bid = blockIdx.x;
    const int xcd = bid & 7;
    const int jb  = bid >> 3;
    const int m   = jb & 63;
    const int g   = (jb >> 6) * 8 + xcd;
    const int b   = g >> 3;
    const int p0  = (g & 7) * NP;

    if (tid <= NP) {
        char* z = PtL + tid * PT_STRIDE + (tid < NP ? 288 : 0);
        *(int4*)z = (int4){0, 0, 0, 0};
    }

    short8 a1[2][5];
    #pragma unroll
    for (int rt = 0; rt < 2; ++rt) {
        const int row = wid * 32 + rt * 16 + lr;
        const float* wr = w1 + (m * Hd + row) * K9;
        #pragma unroll
        for (int ks = 0; ks < 5; ++ks) {
            const int k0 = ks * 32 + lk * 8;
            short8 t;
            if (k0 < K9) {
                const float4 f0 = *(const float4*)(wr + k0);
                const float4 f1 = *(const float4*)(wr + k0 + 4);
                t[0] = (short)f2bf(f0.x); t[1] = (short)f2bf(f0.y);
                t[2] = (short)f2bf(f0.z); t[3] = (short)f2bf(f0.w);
                t[4] = (short)f2bf(f1.x); t[5] = (short)f2bf(f1.y);
                t[6] = (short)f2bf(f1.z); t[7] = (short)f2bf(f1.w);
            } else t = (short8){0,0,0,0,0,0,0,0};
            a1[rt][ks] = t;
        }
    }
    short8 a2[4];
    #pragma unroll
    for (int ks = 0; ks < 4; ++ks) {
        const float* wr = w2 + (m * Cn + lr) * Hd + ks * 32 + lk * 8;
        const float4 f0 = *(const float4*)(wr);
        const float4 f1 = *(const float4*)(wr + 4);
        short8 t;
        t[0] = (short)f2bf(f0.x); t[1] = (short)f2bf(f0.y);
        t[2] = (short)f2bf(f0.z); t[3] = (short)f2bf(f0.w);
        t[4] = (short)f2bf(f1.x); t[5] = (short)f2bf(f1.y);
        t[6] = (short)f2bf(f1.z); t[7] = (short)f2bf(f1.w);
        a2[ks] = t;
    }
    {
        const int s     = tid & 7;
        const int kpl   = (tid >> 3) & 7;
        const int r     = tid >> 6;
        const int rbase = (g & 7) * 4 + r;
        const float* xb = x + (size_t)b * (MCn * 1024);
        const unsigned long long TAB = 0xA62918405ull;
        #pragma unroll
        for (int it = 0; it < 9; ++it) {
            const int kp = it * 8 + kpl;
            float4 hv[2];
            #pragma unroll
            for (int half = 0; half < 2; ++half) {
                const int ch = m * K9 + kp * 2 + half;
                const int sh = ch >> 10;
                const int mc = ch & 1023;
                const uint nib = (uint)(TAB >> (4 * sh)) & 15u;
                const int dr = (int)(nib & 3u) - 1;
                const int dc = (int)(nib >> 2) - 1;
                const int row = rbase + dr;
                const int wb  = 4 * s + dc;
                const int wc  = min(max(wb, 0), 28);
                float4 f = {0.f, 0.f, 0.f, 0.f};
                if ((unsigned)row < 32u)
                    f = *(const float4*)(xb + (mc * 32 + row) * 32 + wc);
                if (wb < 0)       { f.w = f.z; f.z = f.y; f.y = f.x; f.x = 0.f; }
                else if (wb > 28) { f.x = f.y; f.y = f.z; f.z = f.w; f.w = 0.f; }
                hv[half] = f;
            }
            char* dst = PtL + (r * 32 + 4 * s) * PT_STRIDE + kp * 4;
            *(uint*)(dst)                 = (uint)f2bf(hv[0].x) | ((uint)f2bf(hv[1].x) << 16);
            *(uint*)(dst + PT_STRIDE)     = (uint)f2bf(hv[0].y) | ((uint)f2bf(hv[1].y) << 16);
            *(uint*)(dst + 2 * PT_STRIDE) = (uint)f2bf(hv[0].z) | ((uint)f2bf(hv[1].z) << 16);
            *(uint*)(dst + 3 * PT_STRIDE) = (uint)f2bf(hv[0].w) | ((uint)f2bf(hv[1].w) << 16);
        }
    }
    __syncthreads();

    f32x4 acc[2][8];
    #pragma unroll
    for (int i = 0; i < 2; ++i)
        #pragma unroll
        for (int jj = 0; jj < 8; ++jj) acc[i][jj] = (f32x4){0.f, 0.f, 0.f, 0.f};
    #pragma unroll
    for (int ct = 0; ct < 8; ++ct) {
        const int p = ct * 16 + lr;
        const char* base = PtL + p * PT_STRIDE + lk * 16;
        short8 bfrag[5];
        #pragma unroll
        for (int ks = 0; ks < 5; ++ks)
            bfrag[ks] = *(const short8*)(base + ks * 64);
        #pragma unroll
        for (int ks = 0; ks < 5; ++ks) {
            acc[0][ct] = __builtin_amdgcn_mfma_f32_16x16x32_bf16(a1[0][ks], bfrag[ks], acc[0][ct], 0, 0, 0);
            acc[1][ct] = __builtin_amdgcn_mfma_f32_16x16x32_bf16(a1[1][ks], bfrag[ks], acc[1][ct], 0, 0, 0);
        }
    }
    __syncthreads();
    #pragma unroll
    for (int rt = 0; rt < 2; ++rt) {
        const int hd0 = wid * 32 + rt * 16 + lk * 4;
        const float4 bs = *(const float4*)(b1 + m * Hd + hd0);
        #pragma unroll
        for (int ct = 0; ct < 8; ++ct) {
            const int p = ct * 16 + lr;
            const f32x4 v = acc[rt][ct];
            uint2 pk;
            pk.x = (uint)f2bf(fmaxf(v[0] + bs.x, 0.f)) |
                   ((uint)f2bf(fmaxf(v[1] + bs.y, 0.f)) << 16);
            pk.y = (uint)f2bf(fmaxf(v[2] + bs.z, 0.f)) |
                   ((uint)f2bf(fmaxf(v[3] + bs.w, 0.f)) << 16);
            *(uint2*)(HtL + p * HT_STRIDE + hd0 * 2) = pk;
        }
    }
    __syncthreads();
    f32x4 acc2[2];
    #pragma unroll
    for (int jj = 0; jj < 2; ++jj) {
        const int ct = wid * 2 + jj;
        const int p  = ct * 16 + lr;
        const char* base = HtL + p * HT_STRIDE + lk * 16;
        short8 bb[4];
        #pragma unroll
        for (int ks = 0; ks < 4; ++ks)
            bb[ks] = *(const short8*)(base + ks * 64);
        f32x4 a = (f32x4){0.f, 0.f, 0.f, 0.f};
        #pragma unroll
        for (int ks = 0; ks < 4; ++ks)
            a = __builtin_amdgcn_mfma_f32_16x16x32_bf16(a2[ks], bb[ks], a, 0, 0, 0);
        acc2[jj] = a;
    }
    const float4 b2v = *(const float4*)(b2 + m * Cn + lk * 4);
    const float bsv[4] = {b2v.x, b2v.y, b2v.z, b2v.w};
    #pragma unroll
    for (int jj = 0; jj < 2; ++jj) {
        const int ct = wid * 2 + jj;
        const int gp = p0 + ct * 16 + lr;
        #pragma unroll
        for (int r = 0; r < 4; ++r) {
            const int c   = lk * 4 + r;
            const size_t idx = ((size_t)(b * MCn + m * Cn + c)) * 1024 + gp;
            out[idx] = x[idx] + acc2[jj][r] + bsv[r];
        }
    }
}

extern "C" void kernel_launch(void* const* d_in, const int* in_sizes, int n_in,
                              void* d_out, int out_size, void* d_ws, size_t ws_size,
                              hipStream_t stream)
{
    const float* x  = (const float*)d_in[0];
    const float* w1 = (const float*)d_in[1];
    const float* b1 = (const float*)d_in[2];
    const float* w2 = (const float*)d_in[3];
    const float* b2 = (const float*)d_in[4];
    float* out = (float*)d_out;
    const int grid = Mn * (Bn * 1024 / NP);   // 8192

    if (ws_size >= WS_NEED) {
        ushort* xpm  = (ushort*)d_ws;
        ushort* w1bf = (ushort*)((char*)d_ws + XPM_BYTES);
        ushort* w2bf = w1bf + W1_ELEMS;
        prep_xpm<<<Bn * 32 * 4, 256, 0, stream>>>(x, xpm);
        prep_border<<<Bn * 132, 128, 0, stream>>>(xpm);
        prep_w<<<(int)((W1_ELEMS + W2_ELEMS) / 4 / 256), 256, 0, stream>>>(w1, w2, w1bf, w2bf);
        nca_mfma_pm<<<grid, NT, 0, stream>>>(xpm, w1bf, b1, w2bf, b2, out);
    } else {
        nca_mfma_f32src<<<grid, NT, 0, stream>>>(x, w1, b1, w2, b2, out);
    }
}